// Round 6
// baseline (134.095 us; speedup 1.0000x reference)
//
#include <hip/hip_runtime.h>

// DatasetProjector: per-example Conv1d(200ch->512-of-4096, k=3, pad=1) + bias + GELU,
// computing only dataset_id[b]'s 512-channel slice (8x algebraic cut).
//
// R6: software-pipelined K-loop (cp.async style). Double-buffered LDS for both x and W
// tiles; chunk c+1's global_load_lds issued BEFORE compute(c), so the vmcnt(0) drain at
// the single per-chunk barrier lands after a full compute phase (~exposed latency -> 0).
// 64m x 256t block tile (acc[4][4] per wave, 57.6 KB LDS -> 2 blocks/CU, grid 1024 =
// 2 rounds). R4/R5's conflict-free granule swizzle retained (measured 0 conflicts).
// Note: ~60-80us/iter of total dur is harness d_ws/d_out re-poison fills (uncontrollable).

typedef unsigned short u16;
typedef __attribute__((ext_vector_type(8))) short bf16x8;
typedef __attribute__((ext_vector_type(4))) float f32x4;

#define CIN 200
#define CINP 224        // padded channels = 7 chunks of 32
#define T 1024
#define BATCH 32
#define MD 512
#define XT_ROWS 1026    // row t1 = t+1; rows 0 and 1025 are zeros
#define NCHUNK 7
#define XP_PITCH 202    // prep LDS pitch in u16 -> 101 dwords (odd => conflict-free)
#define MW 64           // m per block
#define TT 256          // t per block
#define XROWS (TT + 2)  // 258 staged x rows (t0-1 .. t0+256)
#define XGRAN (XROWS * 4)   // 1032 granules = 16.5 KB per buffer
#define WGRAN (3 * MW * 4)  // 768 granules  = 12.3 KB per buffer

__device__ __forceinline__ u16 f2bf(float f) {
    unsigned u = __float_as_uint(f);
    u += 0x7FFFu + ((u >> 16) & 1u);   // RNE
    return (u16)(u >> 16);
}

// async global(16B) -> LDS, dest = wave-uniform base + lane*16
__device__ __forceinline__ void g2l16(void* lds, const void* g) {
    __builtin_amdgcn_global_load_lds(
        (const __attribute__((address_space(1))) unsigned int*)(uintptr_t)g,
        (__attribute__((address_space(3))) unsigned int*)(unsigned)(uintptr_t)lds,
        16, 0, 0);
}

// ---- fused prep: blocks [0,512) transpose x -> xt[b][t+1][224] bf16;
//      blocks [512, 512+3584) transform W[o][i][k] -> wt[o][k][224] bf16 ----
__global__ __launch_bounds__(256) void prep(const float* __restrict__ x,
                                            const float* __restrict__ W,
                                            u16* __restrict__ xt,
                                            u16* __restrict__ wt) {
    __shared__ u16 tile[64 * XP_PITCH];
    const int tid = threadIdx.x;
    if (blockIdx.x < 512) {
        const int b  = blockIdx.x >> 4;
        const int bx = blockIdx.x & 15;
        const int t0 = bx * 64;
        const int tl = tid & 63;       // t within tile (lane -> coalesced x reads)
        const int w  = tid >> 6;
        const float* xb = x + (size_t)b * CIN * T + t0 + tl;
        for (int i = w; i < CIN; i += 4)                 // pitch 101 dwords (odd) -> conflict-free
            tile[tl * XP_PITCH + i] = f2bf(xb[(size_t)i * T]);
        __syncthreads();
        u16* xrow = xt + ((size_t)b * XT_ROWS + 1 + t0) * CINP;
        for (int it = 0; it < 16; ++it) {
            int r = it * 4 + w;
            if (tl < 56) {                               // 56 lanes x ushort4 = 224 ch
                ushort4 v = {0, 0, 0, 0};
                if (tl < 50) {                           // 50*4 = 200 valid channels
                    const u16* p = tile + r * XP_PITCH + tl * 4;
                    v.x = p[0]; v.y = p[1]; v.z = p[2]; v.w = p[3];
                }
                *(ushort4*)(xrow + (size_t)r * CINP + tl * 4) = v;
            }
        }
        if (bx == 0 && tid < 112)
            ((unsigned*)(xt + (size_t)b * XT_ROWS * CINP))[tid] = 0;          // t = -1 row
        if (bx == 15 && tid < 112)
            ((unsigned*)(xt + ((size_t)b * XT_ROWS + 1025) * CINP))[tid] = 0; // t = 1024 row
    } else {
        int idx = (blockIdx.x - 512) * 256 + tid;        // over 4096*224
        int o = idx / CINP;
        int i = idx - o * CINP;                          // i < 224 < 256 always valid in W
        const float* wp = W + (size_t)o * 768 + i * 3;   // 3 contiguous floats
        u16* wo = wt + (size_t)o * 3 * CINP + i;
        float w0 = wp[0], w1 = wp[1], w2 = wp[2];
        wo[0]        = f2bf(w0);
        wo[CINP]     = f2bf(w1);
        wo[2 * CINP] = f2bf(w2);
    }
}

// ---- main: per-example MFMA conv-GEMM, 64m x 256t per block, 1024 blocks ----
// LDS granule swizzle: logical (row, seg s) -> granule row*4 + (s ^ ((row>>1)&3));
// swizzle lives in the *global* gather address so global_load_lds (contiguous lane-order
// dest) and ds_read_b128 frag reads are both conflict-free (measured 0 in R4/R5).
__global__ __launch_bounds__(256) void conv_mfma(const u16* __restrict__ xt,
                                                 const u16* __restrict__ wt,
                                                 const int* __restrict__ dsid,
                                                 const float* __restrict__ bias,
                                                 float* __restrict__ out) {
    __shared__ __align__(16) u16 xs[2][XGRAN * 8];    // 2 x 16.5 KB
    __shared__ __align__(16) u16 wsm[2][WGRAN * 8];   // 2 x 12.3 KB

    const int tid = threadIdx.x;
    const int wave = tid >> 6, lane = tid & 63;
    const int l = lane & 15, quad = lane >> 4;
    const int wti = wave * 64;             // wave t offset; all waves cover full 64 m

    // XCD swizzle: the 8 m-blocks sharing one (b,t) xt slice have ids differing only in
    // bits 3..5 -> same (id & 7) -> same XCD -> xt tile (115 KB) served from that XCD's L2.
    const int id = blockIdx.x;
    const int m0 = ((id >> 3) & 7) * MW;
    const int tb = (id >> 6) * 8 + (id & 7);   // 0..127 = (b, tloc)
    const int t0 = (tb & 3) * TT;
    const int b  = tb >> 2;
    const int d  = dsid[b];
    const int obase = d * MD + m0;

    f32x4 acc[4][4];
#pragma unroll
    for (int mi = 0; mi < 4; ++mi)
#pragma unroll
        for (int ti = 0; ti < 4; ++ti) acc[mi][ti] = (f32x4){0.f, 0.f, 0.f, 0.f};

    const u16* xbase = xt + ((size_t)b * XT_ROWS + t0) * CINP;  // row r -> t = t0+r-1
    const u16* wbase = wt + (size_t)obase * 3 * CINP;

    // hoisted staging addresses (chunk-invariant); chunk advance = +32 u16 = 64 B
    const u16* xsrc[5]; unsigned xdo[5];
#pragma unroll
    for (int k = 0; k < 5; ++k) {
        int g = tid + k * 256;
        int r = g >> 2, p = g & 3, s = p ^ ((r >> 1) & 3);
        if (g < XGRAN) { xsrc[k] = xbase + (size_t)r * CINP + s * 8; xdo[k] = (unsigned)(g & ~63) * 8; }
        else           { xsrc[k] = xbase;                            xdo[k] = 0; }
    }
    const u16* wsrc[3]; unsigned wdo[3];
#pragma unroll
    for (int k = 0; k < 3; ++k) {
        int g = tid + k * 256;
        int p = g & 3, row = g >> 2;           // row = tap*64 + m
        int m = row & 63, tap = row >> 6;
        int s = p ^ ((row >> 1) & 3);
        wsrc[k] = wbase + ((size_t)m * 3 + tap) * CINP + s * 8;
        wdo[k] = (unsigned)(g & ~63) * 8;
    }

    // ---- software pipeline: stage(c+1) issued before compute(c) ----
    // prologue: stage chunk 0 into buffer 0
#pragma unroll
    for (int k = 0; k < 5; ++k)
        if (tid + k * 256 < XGRAN) g2l16(&xs[0][0] + xdo[k], xsrc[k]);
#pragma unroll
    for (int k = 0; k < 3; ++k)
        g2l16(&wsm[0][0] + wdo[k], wsrc[k]);

    for (int c = 0; c < NCHUNK; ++c) {
        const int cur = c & 1;
        __syncthreads();   // completes stage(c); its loads had compute(c-1) to land

        if (c + 1 < NCHUNK) {
            const int ic = (c + 1) * 32;
            const int nxt = cur ^ 1;
#pragma unroll
            for (int k = 0; k < 5; ++k)
                if (tid + k * 256 < XGRAN) g2l16(&xs[nxt][0] + xdo[k], xsrc[k] + ic);
#pragma unroll
            for (int k = 0; k < 3; ++k)
                g2l16(&wsm[nxt][0] + wdo[k], wsrc[k] + ic);
        }

        const u16* xb = &xs[cur][0];
        const u16* wb = &wsm[cur][0];
#pragma unroll
        for (int tap = 0; tap < 3; ++tap) {
            bf16x8 a[4];
#pragma unroll
            for (int mi = 0; mi < 4; ++mi) {
                int mr = tap * 64 + mi * 16 + l;
                a[mi] = *(const bf16x8*)(wb + ((size_t)mr * 4 + (quad ^ ((mr >> 1) & 3))) * 8);
            }
#pragma unroll
            for (int ti = 0; ti < 4; ++ti) {
                int row = wti + ti * 16 + l + tap;
                bf16x8 bv = *(const bf16x8*)(xb + ((size_t)row * 4 + (quad ^ ((row >> 1) & 3))) * 8);
#pragma unroll
                for (int mi = 0; mi < 4; ++mi)
                    acc[mi][ti] = __builtin_amdgcn_mfma_f32_16x16x32_bf16(a[mi], bv, acc[mi][ti], 0, 0, 0);
            }
        }
    }

    // epilogue: +bias, sigmoid-form tanh-GELU (exp2-folded, branchless), f32 store
#pragma unroll
    for (int mi = 0; mi < 4; ++mi) {
        float bv[4];
#pragma unroll
        for (int r = 0; r < 4; ++r)
            bv[r] = bias[obase + mi * 16 + quad * 4 + r];
#pragma unroll
        for (int ti = 0; ti < 4; ++ti) {
            int t = t0 + wti + ti * 16 + l;
#pragma unroll
            for (int r = 0; r < 4; ++r) {
                int m = mi * 16 + quad * 4 + r;
                float v = acc[mi][ti][r] + bv[r];
                float p2 = v * v;
                // exp(-z), z = v*(1.59577 + 0.0713548 v^2), folded to exp2
                float z2 = v * fmaf(p2, -0.10295089f, -2.30243665f);
                float e = __builtin_amdgcn_exp2f(z2);
                float g = v * __builtin_amdgcn_rcpf(1.0f + e);   // v * sigmoid(z)
                out[((size_t)(b * MD + m0 + m)) * T + t] = g;
            }
        }
    }
}

extern "C" void kernel_launch(void* const* d_in, const int* in_sizes, int n_in,
                              void* d_out, int out_size, void* d_ws, size_t ws_size,
                              hipStream_t stream) {
    const float* x    = (const float*)d_in[0];
    const int*   dsid = (const int*)d_in[1];
    const float* W    = (const float*)d_in[2];
    const float* bias = (const float*)d_in[3];
    float* out = (float*)d_out;

    u16* xt = (u16*)d_ws;                                // 32*1026*224*2 = 14.7 MB
    u16* wt = xt + (size_t)BATCH * XT_ROWS * CINP;       // 4096*672*2   =  5.5 MB

    prep<<<512 + 3584, 256, 0, stream>>>(x, W, xt, wt);
    conv_mfma<<<1024, 256, 0, stream>>>(xt, wt, dsid, bias, out);
}